// Round 1
// baseline (2913.477 us; speedup 1.0000x reference)
//
#include <hip/hip_runtime.h>

#define N_NODES 100000
#define N_EDGES 1600000
#define IN_DIM  256
#define OUT_DIM 128

// ---------------------------------------------------------------------------
// GEMM: h[M][128] = x[M][256] @ W[128][256]^T   (f32, VALU — no f32 MFMA on CDNA4)
// Block: 256 threads. Tile: 16 rows of x (LDS), all 128 output cols.
// Thread t: col c = t&127, row offset rb = t>>7; computes 8 rows (rb, rb+2, ...).
// W row c read as float4 stream (per-thread sequential -> L1-friendly, W is L2-resident).
// ---------------------------------------------------------------------------
__global__ __launch_bounds__(256) void gemm_xwT(const float* __restrict__ x,
                                                const float* __restrict__ W,
                                                float* __restrict__ h) {
    __shared__ float xs[16][IN_DIM];
    const int m0 = blockIdx.x * 16;

    // cooperative x-tile load: 16*256 floats = 1024 float4, 256 threads -> 4 each
    const float4* xsrc = (const float4*)(x + (size_t)m0 * IN_DIM);
    float4* xdst = (float4*)(&xs[0][0]);
#pragma unroll
    for (int i = 0; i < 4; ++i)
        xdst[threadIdx.x + i * 256] = xsrc[threadIdx.x + i * 256];
    __syncthreads();

    const int c  = threadIdx.x & 127;
    const int rb = threadIdx.x >> 7;   // 0 or 1

    float acc[8] = {0.f, 0.f, 0.f, 0.f, 0.f, 0.f, 0.f, 0.f};
    const float4* wv = (const float4*)(W + (size_t)c * IN_DIM);

#pragma unroll 4
    for (int k4 = 0; k4 < IN_DIM / 4; ++k4) {
        float4 w = wv[k4];
#pragma unroll
        for (int r = 0; r < 8; ++r) {
            const float4 xv = *(const float4*)(&xs[rb + 2 * r][k4 * 4]);  // broadcast read
            acc[r] += xv.x * w.x + xv.y * w.y + xv.z * w.z + xv.w * w.w;
        }
    }

#pragma unroll
    for (int r = 0; r < 8; ++r)
        h[(size_t)(m0 + rb + 2 * r) * OUT_DIM + c] = acc[r];
}

// ---------------------------------------------------------------------------
// Scatter: out[row[e]] += val[e] * h[col[e]]   via HW f32 atomics.
// 32 lanes per edge, float4 per lane (covers 128 channels).
// 8 edges per 256-thread block per grid-stride step.
// h (51 MB) and out (51 MB) are Infinity-Cache resident.
// ---------------------------------------------------------------------------
__global__ __launch_bounds__(256) void spmm_scatter(const float* __restrict__ h,
                                                    const int* __restrict__ erow,
                                                    const int* __restrict__ ecol,
                                                    const float* __restrict__ eval,
                                                    float* __restrict__ out) {
    const int lane   = threadIdx.x & 31;
    const int eloc   = threadIdx.x >> 5;               // 0..7
    const int stride = gridDim.x * 8;

    for (int e = blockIdx.x * 8 + eloc; e < N_EDGES; e += stride) {
        const int   r = erow[e];
        const int   c = ecol[e];
        const float v = eval[e];

        const float4 hv = *(const float4*)(h + (size_t)c * OUT_DIM + lane * 4);
        float* o = out + (size_t)r * OUT_DIM + lane * 4;

        unsafeAtomicAdd(o + 0, hv.x * v);
        unsafeAtomicAdd(o + 1, hv.y * v);
        unsafeAtomicAdd(o + 2, hv.z * v);
        unsafeAtomicAdd(o + 3, hv.w * v);
    }
}

extern "C" void kernel_launch(void* const* d_in, const int* in_sizes, int n_in,
                              void* d_out, int out_size, void* d_ws, size_t ws_size,
                              hipStream_t stream) {
    const float* x    = (const float*)d_in[0];
    const float* W    = (const float*)d_in[1];
    const int*   erow = (const int*)d_in[2];
    const int*   ecol = (const int*)d_in[3];
    const float* eval = (const float*)d_in[4];
    float*       out  = (float*)d_out;
    float*       h    = (float*)d_ws;   // 100000*128*4 = 51.2 MB scratch

    // out is accumulated atomically -> must start at zero every call
    hipMemsetAsync(d_out, 0, (size_t)out_size * sizeof(float), stream);

    gemm_xwT<<<N_NODES / 16, 256, 0, stream>>>(x, W, h);
    spmm_scatter<<<4096, 256, 0, stream>>>(h, erow, ecol, eval, out);
}

// Round 2
// 505.171 us; speedup vs baseline: 5.7673x; 5.7673x over previous
//
#include <hip/hip_runtime.h>

#define N_NODES 100000
#define N_EDGES 1600000
#define IN_DIM  256
#define OUT_DIM 128

#define SCAN_CHUNK 1024
#define NB_SCAN    98          // ceil(100000/1024) -> covers 100352 padded entries
#define PAD_NODES  (NB_SCAN * SCAN_CHUNK)   // 100352

// ---------------------------------------------------------------------------
// GEMM: h[M][128] = x[M][256] @ W[128][256]^T  (unchanged from R1)
// ---------------------------------------------------------------------------
__global__ __launch_bounds__(256) void gemm_xwT(const float* __restrict__ x,
                                                const float* __restrict__ W,
                                                float* __restrict__ h) {
    __shared__ float xs[16][IN_DIM];
    const int m0 = blockIdx.x * 16;

    const float4* xsrc = (const float4*)(x + (size_t)m0 * IN_DIM);
    float4* xdst = (float4*)(&xs[0][0]);
#pragma unroll
    for (int i = 0; i < 4; ++i)
        xdst[threadIdx.x + i * 256] = xsrc[threadIdx.x + i * 256];
    __syncthreads();

    const int c  = threadIdx.x & 127;
    const int rb = threadIdx.x >> 7;

    float acc[8] = {0.f, 0.f, 0.f, 0.f, 0.f, 0.f, 0.f, 0.f};
    const float4* wv = (const float4*)(W + (size_t)c * IN_DIM);

#pragma unroll 4
    for (int k4 = 0; k4 < IN_DIM / 4; ++k4) {
        float4 w = wv[k4];
#pragma unroll
        for (int r = 0; r < 8; ++r) {
            const float4 xv = *(const float4*)(&xs[rb + 2 * r][k4 * 4]);
            acc[r] += xv.x * w.x + xv.y * w.y + xv.z * w.z + xv.w * w.w;
        }
    }

#pragma unroll
    for (int r = 0; r < 8; ++r)
        h[(size_t)(m0 + rb + 2 * r) * OUT_DIM + c] = acc[r];
}

// ---------------------------------------------------------------------------
// CSR build: histogram -> per-chunk exclusive scan -> chunk-sum scan -> fill
// ---------------------------------------------------------------------------
__global__ __launch_bounds__(256) void hist_rows(const int* __restrict__ erow,
                                                 int* __restrict__ cnt) {
    int e = blockIdx.x * 256 + threadIdx.x;
    if (e < N_EDGES) atomicAdd(&cnt[erow[e]], 1);
}

// Per-chunk (1024 elems) exclusive scan; block sum to bsum[b].
__global__ __launch_bounds__(256) void scan_blocks(const int* __restrict__ cnt,
                                                   int* __restrict__ offs,
                                                   int* __restrict__ bsum) {
    __shared__ int tmp[256];
    const int t = threadIdx.x;
    const int base = blockIdx.x * SCAN_CHUNK + t * 4;
    int4 v = *(const int4*)(cnt + base);
    int s0 = v.x, s1 = s0 + v.y, s2 = s1 + v.z, s3 = s2 + v.w;  // inclusive in 4
    tmp[t] = s3;
    __syncthreads();
    for (int d = 1; d < 256; d <<= 1) {
        int add = (t >= d) ? tmp[t - d] : 0;
        __syncthreads();
        tmp[t] += add;
        __syncthreads();
    }
    int excl = (t == 0) ? 0 : tmp[t - 1];
    int4 o;
    o.x = excl; o.y = excl + s0; o.z = excl + s1; o.w = excl + s2;
    *(int4*)(offs + base) = o;
    if (t == 255) bsum[blockIdx.x] = tmp[255];
}

__global__ void scan_bsums(int* bsum) {
    if (blockIdx.x == 0 && threadIdx.x == 0) {
        int acc = 0;
        for (int i = 0; i < NB_SCAN; ++i) { int v = bsum[i]; bsum[i] = acc; acc += v; }
    }
}

__global__ __launch_bounds__(256) void fill_csr(const int* __restrict__ erow,
                                                const int* __restrict__ ecol,
                                                const float* __restrict__ eval,
                                                const int* __restrict__ offs,
                                                const int* __restrict__ bsum,
                                                int* __restrict__ cur,
                                                int* __restrict__ ccol,
                                                float* __restrict__ cval) {
    int e = blockIdx.x * 256 + threadIdx.x;
    if (e >= N_EDGES) return;
    int r = erow[e];
    int pos = offs[r] + bsum[r >> 10] + atomicAdd(&cur[r], 1);
    ccol[pos] = ecol[e];
    cval[pos] = eval[e];
}

// ---------------------------------------------------------------------------
// Gather: one wave (64 lanes) per output row; lane owns 2 channels (float2).
// Single coalesced store per row -> zero f32 atomics.
// ---------------------------------------------------------------------------
__global__ __launch_bounds__(256) void spmm_gather(const float* __restrict__ h,
                                                   const int* __restrict__ offs,
                                                   const int* __restrict__ bsum,
                                                   const int* __restrict__ ccol,
                                                   const float* __restrict__ cval,
                                                   float* __restrict__ out) {
    const int r = blockIdx.x * 4 + (threadIdx.x >> 6);
    if (r >= N_NODES) return;
    const int lane = threadIdx.x & 63;

    int j   = offs[r]     + bsum[r >> 10];
    int end = offs[r + 1] + bsum[(r + 1) >> 10];

    float2 acc = {0.f, 0.f};
    for (; j + 1 < end; j += 2) {
        int   c0 = ccol[j],  c1 = ccol[j + 1];
        float v0 = cval[j],  v1 = cval[j + 1];
        const float2 h0 = *(const float2*)(h + (size_t)c0 * OUT_DIM + lane * 2);
        const float2 h1 = *(const float2*)(h + (size_t)c1 * OUT_DIM + lane * 2);
        acc.x += v0 * h0.x + v1 * h1.x;
        acc.y += v0 * h0.y + v1 * h1.y;
    }
    if (j < end) {
        int   c0 = ccol[j];
        float v0 = cval[j];
        const float2 h0 = *(const float2*)(h + (size_t)c0 * OUT_DIM + lane * 2);
        acc.x += v0 * h0.x;
        acc.y += v0 * h0.y;
    }
    *(float2*)(out + (size_t)r * OUT_DIM + lane * 2) = acc;
}

// ---------------------------------------------------------------------------
// Fallback scatter (R1 path) if workspace too small for CSR.
// ---------------------------------------------------------------------------
__global__ __launch_bounds__(256) void spmm_scatter(const float* __restrict__ h,
                                                    const int* __restrict__ erow,
                                                    const int* __restrict__ ecol,
                                                    const float* __restrict__ eval,
                                                    float* __restrict__ out) {
    const int lane = threadIdx.x & 31;
    const int eloc = threadIdx.x >> 5;
    const int stride = gridDim.x * 8;
    for (int e = blockIdx.x * 8 + eloc; e < N_EDGES; e += stride) {
        const int r = erow[e];
        const int c = ecol[e];
        const float v = eval[e];
        const float4 hv = *(const float4*)(h + (size_t)c * OUT_DIM + lane * 4);
        float* o = out + (size_t)r * OUT_DIM + lane * 4;
        unsafeAtomicAdd(o + 0, hv.x * v);
        unsafeAtomicAdd(o + 1, hv.y * v);
        unsafeAtomicAdd(o + 2, hv.z * v);
        unsafeAtomicAdd(o + 3, hv.w * v);
    }
}

extern "C" void kernel_launch(void* const* d_in, const int* in_sizes, int n_in,
                              void* d_out, int out_size, void* d_ws, size_t ws_size,
                              hipStream_t stream) {
    const float* x    = (const float*)d_in[0];
    const float* W    = (const float*)d_in[1];
    const int*   erow = (const int*)d_in[2];
    const int*   ecol = (const int*)d_in[3];
    const float* eval = (const float*)d_in[4];
    float*       out  = (float*)d_out;

    // workspace layout (element offsets)
    const size_t H_ELEMS = (size_t)N_NODES * OUT_DIM;          // 12,800,000 f32
    float* h    = (float*)d_ws;
    int*   offs = (int*)(h + H_ELEMS);                         // PAD_NODES ints
    int*   cur  = offs + PAD_NODES;                            // PAD_NODES ints
    int*   bsum = cur + PAD_NODES;                             // 128 ints
    int*   ccol = bsum + 128;                                  // N_EDGES ints
    float* cval = (float*)(ccol + N_EDGES);                    // N_EDGES f32
    const size_t need = ((char*)(cval + N_EDGES)) - (char*)d_ws;

    gemm_xwT<<<N_NODES / 16, 256, 0, stream>>>(x, W, h);

    if (ws_size >= need) {
        // CSR build
        hipMemsetAsync(cur, 0, PAD_NODES * sizeof(int), stream);
        hist_rows<<<(N_EDGES + 255) / 256, 256, 0, stream>>>(erow, cur);
        scan_blocks<<<NB_SCAN, 256, 0, stream>>>(cur, offs, bsum);
        scan_bsums<<<1, 64, 0, stream>>>(bsum);
        hipMemsetAsync(cur, 0, PAD_NODES * sizeof(int), stream);
        fill_csr<<<(N_EDGES + 255) / 256, 256, 0, stream>>>(erow, ecol, eval,
                                                            offs, bsum, cur, ccol, cval);
        // gather: 4 rows per 256-thread block
        spmm_gather<<<N_NODES / 4, 256, 0, stream>>>(h, offs, bsum, ccol, cval, out);
    } else {
        hipMemsetAsync(d_out, 0, (size_t)out_size * sizeof(float), stream);
        spmm_scatter<<<4096, 256, 0, stream>>>(h, erow, ecol, eval, out);
    }
}

// Round 3
// 355.019 us; speedup vs baseline: 8.2065x; 1.4229x over previous
//
#include <hip/hip_runtime.h>

#define N_NODES 100000
#define N_EDGES 1600000
#define IN_DIM  256
#define OUT_DIM 128

#define SCAN_CHUNK 1024
#define NB_SCAN    98          // ceil(100000/1024)
#define PAD_NODES  (NB_SCAN * SCAN_CHUNK)   // 100352

typedef __attribute__((ext_vector_type(8))) short short8;
typedef __attribute__((ext_vector_type(4))) float f32x4;

// f32 -> bf16 round-to-nearest-even (bit trick)
__device__ __forceinline__ unsigned short f2bf(float f) {
    unsigned int u = __float_as_uint(f);
    u += 0x7FFFu + ((u >> 16) & 1u);
    return (unsigned short)(u >> 16);
}

__device__ __forceinline__ short8 pack8(float4 a, float4 b) {
    short8 s;
    s[0] = (short)f2bf(a.x); s[1] = (short)f2bf(a.y);
    s[2] = (short)f2bf(a.z); s[3] = (short)f2bf(a.w);
    s[4] = (short)f2bf(b.x); s[5] = (short)f2bf(b.y);
    s[6] = (short)f2bf(b.z); s[7] = (short)f2bf(b.w);
    return s;
}

// ---------------------------------------------------------------------------
// W (f32 [128][256]) -> bf16 [128][256]
// ---------------------------------------------------------------------------
__global__ __launch_bounds__(256) void w_to_bf16(const float* __restrict__ W,
                                                 unsigned short* __restrict__ Wb) {
    int i = blockIdx.x * 256 + threadIdx.x;
    if (i < OUT_DIM * IN_DIM) Wb[i] = f2bf(W[i]);
}

// ---------------------------------------------------------------------------
// GEMM via bf16 MFMA: h[M][128] = x[M][256] @ W[128][256]^T, f32 accumulate.
// Block: 512 thr (8 waves). BM=128 rows staged as bf16 in XOR-swizzled LDS.
// Wave w owns col-tile w (16 cols); B-frags (W rows) held in registers
// (loaded from L2-resident Wb). Row-tiles processed in pairs (2 acc chains).
// mfma_f32_16x16x32_bf16 layout: A row = lane&15, k = (lane>>4)*8+j;
// B col = lane&15, same k; D row = (lane>>4)*4+i, col = lane&15.
// LDS swizzle: byte ^= (row&7)<<4  -> granule-uniform ds_read_b128 (T2-style).
// ---------------------------------------------------------------------------
__global__ __launch_bounds__(512) void gemm_mfma(const float* __restrict__ x,
                                                 const unsigned short* __restrict__ Wb,
                                                 float* __restrict__ h) {
    __shared__ unsigned short xs[128 * 256];   // 64 KB, swizzled
    const int m0  = blockIdx.x * 128;
    const int tid = threadIdx.x;

    // ---- stage x tile: thread -> row=tid>>2, 64-col segment ----
    {
        const int row = tid >> 2;
        const int cs  = (tid & 3) * 64;
        const int gr  = m0 + row;
        char* lb = (char*)xs;
        if (gr < N_NODES) {
            const float4* src = (const float4*)(x + (size_t)gr * IN_DIM + cs);
#pragma unroll
            for (int i = 0; i < 8; ++i) {
                float4 a = src[2 * i], b = src[2 * i + 1];
                int byt = (row * 512 + (cs + 8 * i) * 2) ^ ((row & 7) << 4);
                *(short8*)(lb + byt) = pack8(a, b);
            }
        } else {
            short8 z = {0, 0, 0, 0, 0, 0, 0, 0};
#pragma unroll
            for (int i = 0; i < 8; ++i) {
                int byt = (row * 512 + (cs + 8 * i) * 2) ^ ((row & 7) << 4);
                *(short8*)(lb + byt) = z;
            }
        }
    }
    __syncthreads();

    const int wid  = tid >> 6;
    const int lane = tid & 63;
    const int l15  = lane & 15;
    const int g8   = (lane >> 4) * 8;   // k-offset of this lane's frag

    // ---- B fragments: W rows (wid*16 + l15), all 8 k-steps, from global (L2) ----
    short8 bf[8];
    const unsigned short* wrow = Wb + (size_t)(wid * 16 + l15) * IN_DIM + g8;
#pragma unroll
    for (int kk = 0; kk < 8; ++kk)
        bf[kk] = *(const short8*)(wrow + kk * 32);

    const int col = wid * 16 + l15;
    const char* lb = (const char*)xs;
    const int sw = (l15 & 7) << 4;      // (row&7)<<4 for rows r0/r1 below

#pragma unroll
    for (int rp = 0; rp < 4; ++rp) {
        const int r0 = rp * 32 + l15;
        const int r1 = r0 + 16;
        short8 a0[8], a1[8];
#pragma unroll
        for (int kk = 0; kk < 8; ++kk) {
            a0[kk] = *(const short8*)(lb + ((r0 * 512 + (kk * 32 + g8) * 2) ^ sw));
            a1[kk] = *(const short8*)(lb + ((r1 * 512 + (kk * 32 + g8) * 2) ^ sw));
        }
        f32x4 acc0 = {0.f, 0.f, 0.f, 0.f}, acc1 = {0.f, 0.f, 0.f, 0.f};
#pragma unroll
        for (int kk = 0; kk < 8; ++kk) {
            acc0 = __builtin_amdgcn_mfma_f32_16x16x32_bf16(a0[kk], bf[kk], acc0, 0, 0, 0);
            acc1 = __builtin_amdgcn_mfma_f32_16x16x32_bf16(a1[kk], bf[kk], acc1, 0, 0, 0);
        }
        const int rb0 = m0 + rp * 32 + (lane >> 4) * 4;
        const int rb1 = rb0 + 16;
#pragma unroll
        for (int i = 0; i < 4; ++i) {
            if (rb0 + i < N_NODES) h[(size_t)(rb0 + i) * OUT_DIM + col] = acc0[i];
            if (rb1 + i < N_NODES) h[(size_t)(rb1 + i) * OUT_DIM + col] = acc1[i];
        }
    }
}

// ---------------------------------------------------------------------------
// CSR build (unchanged from R2)
// ---------------------------------------------------------------------------
__global__ __launch_bounds__(256) void hist_rows(const int* __restrict__ erow,
                                                 int* __restrict__ cnt) {
    int e = blockIdx.x * 256 + threadIdx.x;
    if (e < N_EDGES) atomicAdd(&cnt[erow[e]], 1);
}

__global__ __launch_bounds__(256) void scan_blocks(const int* __restrict__ cnt,
                                                   int* __restrict__ offs,
                                                   int* __restrict__ bsum) {
    __shared__ int tmp[256];
    const int t = threadIdx.x;
    const int base = blockIdx.x * SCAN_CHUNK + t * 4;
    int4 v = *(const int4*)(cnt + base);
    int s0 = v.x, s1 = s0 + v.y, s2 = s1 + v.z, s3 = s2 + v.w;
    tmp[t] = s3;
    __syncthreads();
    for (int d = 1; d < 256; d <<= 1) {
        int add = (t >= d) ? tmp[t - d] : 0;
        __syncthreads();
        tmp[t] += add;
        __syncthreads();
    }
    int excl = (t == 0) ? 0 : tmp[t - 1];
    int4 o;
    o.x = excl; o.y = excl + s0; o.z = excl + s1; o.w = excl + s2;
    *(int4*)(offs + base) = o;
    if (t == 255) bsum[blockIdx.x] = tmp[255];
}

__global__ void scan_bsums(int* bsum) {
    if (blockIdx.x == 0 && threadIdx.x == 0) {
        int acc = 0;
        for (int i = 0; i < NB_SCAN; ++i) { int v = bsum[i]; bsum[i] = acc; acc += v; }
    }
}

__global__ __launch_bounds__(256) void fill_csr(const int* __restrict__ erow,
                                                const int* __restrict__ ecol,
                                                const float* __restrict__ eval,
                                                const int* __restrict__ offs,
                                                const int* __restrict__ bsum,
                                                int* __restrict__ cur,
                                                int* __restrict__ ccol,
                                                float* __restrict__ cval) {
    int e = blockIdx.x * 256 + threadIdx.x;
    if (e >= N_EDGES) return;
    int r = erow[e];
    int pos = offs[r] + bsum[r >> 10] + atomicAdd(&cur[r], 1);
    ccol[pos] = ecol[e];
    cval[pos] = eval[e];
}

// ---------------------------------------------------------------------------
// Gather (unchanged from R2): one wave per row, float2 per lane.
// ---------------------------------------------------------------------------
__global__ __launch_bounds__(256) void spmm_gather(const float* __restrict__ h,
                                                   const int* __restrict__ offs,
                                                   const int* __restrict__ bsum,
                                                   const int* __restrict__ ccol,
                                                   const float* __restrict__ cval,
                                                   float* __restrict__ out) {
    const int r = blockIdx.x * 4 + (threadIdx.x >> 6);
    if (r >= N_NODES) return;
    const int lane = threadIdx.x & 63;

    int j   = offs[r]     + bsum[r >> 10];
    int end = offs[r + 1] + bsum[(r + 1) >> 10];

    float2 acc = {0.f, 0.f};
    for (; j + 1 < end; j += 2) {
        int   c0 = ccol[j],  c1 = ccol[j + 1];
        float v0 = cval[j],  v1 = cval[j + 1];
        const float2 h0 = *(const float2*)(h + (size_t)c0 * OUT_DIM + lane * 2);
        const float2 h1 = *(const float2*)(h + (size_t)c1 * OUT_DIM + lane * 2);
        acc.x += v0 * h0.x + v1 * h1.x;
        acc.y += v0 * h0.y + v1 * h1.y;
    }
    if (j < end) {
        int   c0 = ccol[j];
        float v0 = cval[j];
        const float2 h0 = *(const float2*)(h + (size_t)c0 * OUT_DIM + lane * 2);
        acc.x += v0 * h0.x;
        acc.y += v0 * h0.y;
    }
    *(float2*)(out + (size_t)r * OUT_DIM + lane * 2) = acc;
}

// ---------------------------------------------------------------------------
// Fallback scatter (R1 path) if workspace too small for CSR.
// ---------------------------------------------------------------------------
__global__ __launch_bounds__(256) void spmm_scatter(const float* __restrict__ h,
                                                    const int* __restrict__ erow,
                                                    const int* __restrict__ ecol,
                                                    const float* __restrict__ eval,
                                                    float* __restrict__ out) {
    const int lane = threadIdx.x & 31;
    const int eloc = threadIdx.x >> 5;
    const int stride = gridDim.x * 8;
    for (int e = blockIdx.x * 8 + eloc; e < N_EDGES; e += stride) {
        const int r = erow[e];
        const int c = ecol[e];
        const float v = eval[e];
        const float4 hv = *(const float4*)(h + (size_t)c * OUT_DIM + lane * 4);
        float* o = out + (size_t)r * OUT_DIM + lane * 4;
        unsafeAtomicAdd(o + 0, hv.x * v);
        unsafeAtomicAdd(o + 1, hv.y * v);
        unsafeAtomicAdd(o + 2, hv.z * v);
        unsafeAtomicAdd(o + 3, hv.w * v);
    }
}

extern "C" void kernel_launch(void* const* d_in, const int* in_sizes, int n_in,
                              void* d_out, int out_size, void* d_ws, size_t ws_size,
                              hipStream_t stream) {
    const float* x    = (const float*)d_in[0];
    const float* W    = (const float*)d_in[1];
    const int*   erow = (const int*)d_in[2];
    const int*   ecol = (const int*)d_in[3];
    const float* eval = (const float*)d_in[4];
    float*       out  = (float*)d_out;

    // workspace layout
    const size_t H_ELEMS = (size_t)N_NODES * OUT_DIM;
    float*          h    = (float*)d_ws;
    unsigned short* Wb   = (unsigned short*)(h + H_ELEMS);       // 32768 bf16
    int*            offs = (int*)(Wb + OUT_DIM * IN_DIM);        // PAD_NODES
    int*            cur  = offs + PAD_NODES;                     // PAD_NODES
    int*            bsum = cur + PAD_NODES;                      // 128
    int*            ccol = bsum + 128;                           // N_EDGES
    float*          cval = (float*)(ccol + N_EDGES);             // N_EDGES
    const size_t need = ((char*)(cval + N_EDGES)) - (char*)d_ws;

    w_to_bf16<<<(OUT_DIM * IN_DIM + 255) / 256, 256, 0, stream>>>(W, Wb);
    gemm_mfma<<<(N_NODES + 127) / 128, 512, 0, stream>>>(x, Wb, h);

    if (ws_size >= need) {
        hipMemsetAsync(cur, 0, PAD_NODES * sizeof(int), stream);
        hist_rows<<<(N_EDGES + 255) / 256, 256, 0, stream>>>(erow, cur);
        scan_blocks<<<NB_SCAN, 256, 0, stream>>>(cur, offs, bsum);
        scan_bsums<<<1, 64, 0, stream>>>(bsum);
        hipMemsetAsync(cur, 0, PAD_NODES * sizeof(int), stream);
        fill_csr<<<(N_EDGES + 255) / 256, 256, 0, stream>>>(erow, ecol, eval,
                                                            offs, bsum, cur, ccol, cval);
        spmm_gather<<<(N_NODES + 3) / 4, 256, 0, stream>>>(h, offs, bsum, ccol, cval, out);
    } else {
        hipMemsetAsync(d_out, 0, (size_t)out_size * sizeof(float), stream);
        spmm_scatter<<<4096, 256, 0, stream>>>(h, erow, ecol, eval, out);
    }
}

// Round 4
// 313.784 us; speedup vs baseline: 9.2850x; 1.1314x over previous
//
#include <hip/hip_runtime.h>

#define N_NODES 100000
#define N_EDGES 1600000
#define IN_DIM  256
#define OUT_DIM 128

#define SCAN_CHUNK 1024
#define NB_SCAN    98          // ceil(100000/1024)
#define PAD_NODES  (NB_SCAN * SCAN_CHUNK)   // 100352

typedef __attribute__((ext_vector_type(8))) short short8;
typedef __attribute__((ext_vector_type(4))) float f32x4;

// f32 -> bf16 round-to-nearest-even (bit trick)
__device__ __forceinline__ unsigned short f2bf(float f) {
    unsigned int u = __float_as_uint(f);
    u += 0x7FFFu + ((u >> 16) & 1u);
    return (unsigned short)(u >> 16);
}
__device__ __forceinline__ float bf2f(unsigned int u16) {
    return __uint_as_float(u16 << 16);
}

__device__ __forceinline__ short8 pack8(float4 a, float4 b) {
    short8 s;
    s[0] = (short)f2bf(a.x); s[1] = (short)f2bf(a.y);
    s[2] = (short)f2bf(a.z); s[3] = (short)f2bf(a.w);
    s[4] = (short)f2bf(b.x); s[5] = (short)f2bf(b.y);
    s[6] = (short)f2bf(b.z); s[7] = (short)f2bf(b.w);
    return s;
}

// ---------------------------------------------------------------------------
// W (f32 [128][256]) -> bf16
// ---------------------------------------------------------------------------
__global__ __launch_bounds__(256) void w_to_bf16(const float* __restrict__ W,
                                                 unsigned short* __restrict__ Wb) {
    int i = blockIdx.x * 256 + threadIdx.x;
    if (i < OUT_DIM * IN_DIM) Wb[i] = f2bf(W[i]);
}

// ---------------------------------------------------------------------------
// GEMM via bf16 MFMA: hb[M][128] (bf16) = x[M][256] @ W^T, f32 accumulate.
// Same structure as R3; output now stored as bf16 (halves h traffic).
// ---------------------------------------------------------------------------
__global__ __launch_bounds__(512) void gemm_mfma(const float* __restrict__ x,
                                                 const unsigned short* __restrict__ Wb,
                                                 unsigned short* __restrict__ hb) {
    __shared__ unsigned short xs[128 * 256];   // 64 KB, swizzled
    const int m0  = blockIdx.x * 128;
    const int tid = threadIdx.x;

    {
        const int row = tid >> 2;
        const int cs  = (tid & 3) * 64;
        const int gr  = m0 + row;
        char* lb = (char*)xs;
        if (gr < N_NODES) {
            const float4* src = (const float4*)(x + (size_t)gr * IN_DIM + cs);
#pragma unroll
            for (int i = 0; i < 8; ++i) {
                float4 a = src[2 * i], b = src[2 * i + 1];
                int byt = (row * 512 + (cs + 8 * i) * 2) ^ ((row & 7) << 4);
                *(short8*)(lb + byt) = pack8(a, b);
            }
        } else {
            short8 z = {0, 0, 0, 0, 0, 0, 0, 0};
#pragma unroll
            for (int i = 0; i < 8; ++i) {
                int byt = (row * 512 + (cs + 8 * i) * 2) ^ ((row & 7) << 4);
                *(short8*)(lb + byt) = z;
            }
        }
    }
    __syncthreads();

    const int wid  = tid >> 6;
    const int lane = tid & 63;
    const int l15  = lane & 15;
    const int g8   = (lane >> 4) * 8;

    short8 bf[8];
    const unsigned short* wrow = Wb + (size_t)(wid * 16 + l15) * IN_DIM + g8;
#pragma unroll
    for (int kk = 0; kk < 8; ++kk)
        bf[kk] = *(const short8*)(wrow + kk * 32);

    const int col = wid * 16 + l15;
    const char* lb = (const char*)xs;
    const int sw = (l15 & 7) << 4;

#pragma unroll
    for (int rp = 0; rp < 4; ++rp) {
        const int r0 = rp * 32 + l15;
        const int r1 = r0 + 16;
        short8 a0[8], a1[8];
#pragma unroll
        for (int kk = 0; kk < 8; ++kk) {
            a0[kk] = *(const short8*)(lb + ((r0 * 512 + (kk * 32 + g8) * 2) ^ sw));
            a1[kk] = *(const short8*)(lb + ((r1 * 512 + (kk * 32 + g8) * 2) ^ sw));
        }
        f32x4 acc0 = {0.f, 0.f, 0.f, 0.f}, acc1 = {0.f, 0.f, 0.f, 0.f};
#pragma unroll
        for (int kk = 0; kk < 8; ++kk) {
            acc0 = __builtin_amdgcn_mfma_f32_16x16x32_bf16(a0[kk], bf[kk], acc0, 0, 0, 0);
            acc1 = __builtin_amdgcn_mfma_f32_16x16x32_bf16(a1[kk], bf[kk], acc1, 0, 0, 0);
        }
        const int rb0 = m0 + rp * 32 + (lane >> 4) * 4;
        const int rb1 = rb0 + 16;
#pragma unroll
        for (int i = 0; i < 4; ++i) {
            if (rb0 + i < N_NODES) hb[(size_t)(rb0 + i) * OUT_DIM + col] = f2bf(acc0[i]);
            if (rb1 + i < N_NODES) hb[(size_t)(rb1 + i) * OUT_DIM + col] = f2bf(acc1[i]);
        }
    }
}

// ---------------------------------------------------------------------------
// CSR build: histogram -> scan -> fill (fill writes ONE int2 {col,val} per edge)
// ---------------------------------------------------------------------------
__global__ __launch_bounds__(256) void hist_rows(const int* __restrict__ erow,
                                                 int* __restrict__ cnt) {
    int e = blockIdx.x * 256 + threadIdx.x;
    if (e < N_EDGES) atomicAdd(&cnt[erow[e]], 1);
}

__global__ __launch_bounds__(256) void scan_blocks(const int* __restrict__ cnt,
                                                   int* __restrict__ offs,
                                                   int* __restrict__ bsum) {
    __shared__ int tmp[256];
    const int t = threadIdx.x;
    const int base = blockIdx.x * SCAN_CHUNK + t * 4;
    int4 v = *(const int4*)(cnt + base);
    int s0 = v.x, s1 = s0 + v.y, s2 = s1 + v.z, s3 = s2 + v.w;
    tmp[t] = s3;
    __syncthreads();
    for (int d = 1; d < 256; d <<= 1) {
        int add = (t >= d) ? tmp[t - d] : 0;
        __syncthreads();
        tmp[t] += add;
        __syncthreads();
    }
    int excl = (t == 0) ? 0 : tmp[t - 1];
    int4 o;
    o.x = excl; o.y = excl + s0; o.z = excl + s1; o.w = excl + s2;
    *(int4*)(offs + base) = o;
    if (t == 255) bsum[blockIdx.x] = tmp[255];
}

__global__ void scan_bsums(int* bsum) {
    if (blockIdx.x == 0 && threadIdx.x == 0) {
        int acc = 0;
        for (int i = 0; i < NB_SCAN; ++i) { int v = bsum[i]; bsum[i] = acc; acc += v; }
    }
}

__global__ __launch_bounds__(256) void fill_csr(const int* __restrict__ erow,
                                                const int* __restrict__ ecol,
                                                const float* __restrict__ eval,
                                                const int* __restrict__ offs,
                                                const int* __restrict__ bsum,
                                                int* __restrict__ cur,
                                                int2* __restrict__ ccv) {
    int e = blockIdx.x * 256 + threadIdx.x;
    if (e >= N_EDGES) return;
    int r = erow[e];
    int pos = offs[r] + bsum[r >> 10] + atomicAdd(&cur[r], 1);
    ccv[pos] = make_int2(ecol[e], __float_as_int(eval[e]));
}

// ---------------------------------------------------------------------------
// Gather: one wave per row; lane owns 2 channels (one bf16x2 dword of hb).
// ---------------------------------------------------------------------------
__global__ __launch_bounds__(256) void spmm_gather(const unsigned short* __restrict__ hb,
                                                   const int* __restrict__ offs,
                                                   const int* __restrict__ bsum,
                                                   const int2* __restrict__ ccv,
                                                   float* __restrict__ out) {
    const int r = blockIdx.x * 4 + (threadIdx.x >> 6);
    if (r >= N_NODES) return;
    const int lane = threadIdx.x & 63;

    int j   = offs[r]     + bsum[r >> 10];
    int end = offs[r + 1] + bsum[(r + 1) >> 10];

    float ax = 0.f, ay = 0.f;
    for (; j + 1 < end; j += 2) {
        int2 e0 = ccv[j], e1 = ccv[j + 1];
        float v0 = __int_as_float(e0.y), v1 = __int_as_float(e1.y);
        unsigned int p0 = *(const unsigned int*)(hb + (size_t)e0.x * OUT_DIM + lane * 2);
        unsigned int p1 = *(const unsigned int*)(hb + (size_t)e1.x * OUT_DIM + lane * 2);
        ax += v0 * bf2f(p0 & 0xFFFFu) + v1 * bf2f(p1 & 0xFFFFu);
        ay += v0 * bf2f(p0 >> 16)     + v1 * bf2f(p1 >> 16);
    }
    if (j < end) {
        int2 e0 = ccv[j];
        float v0 = __int_as_float(e0.y);
        unsigned int p0 = *(const unsigned int*)(hb + (size_t)e0.x * OUT_DIM + lane * 2);
        ax += v0 * bf2f(p0 & 0xFFFFu);
        ay += v0 * bf2f(p0 >> 16);
    }
    float2 o = {ax, ay};
    *(float2*)(out + (size_t)r * OUT_DIM + lane * 2) = o;
}

// ---------------------------------------------------------------------------
// Fallback scatter (bf16 h) if workspace too small for CSR.
// ---------------------------------------------------------------------------
__global__ __launch_bounds__(256) void spmm_scatter(const unsigned short* __restrict__ hb,
                                                    const int* __restrict__ erow,
                                                    const int* __restrict__ ecol,
                                                    const float* __restrict__ eval,
                                                    float* __restrict__ out) {
    const int lane = threadIdx.x & 63;
    const int eloc = threadIdx.x >> 6;
    const int stride = gridDim.x * 4;
    for (int e = blockIdx.x * 4 + eloc; e < N_EDGES; e += stride) {
        const int r = erow[e];
        const int c = ecol[e];
        const float v = eval[e];
        unsigned int p = *(const unsigned int*)(hb + (size_t)c * OUT_DIM + lane * 2);
        float* o = out + (size_t)r * OUT_DIM + lane * 2;
        unsafeAtomicAdd(o + 0, v * bf2f(p & 0xFFFFu));
        unsafeAtomicAdd(o + 1, v * bf2f(p >> 16));
    }
}

extern "C" void kernel_launch(void* const* d_in, const int* in_sizes, int n_in,
                              void* d_out, int out_size, void* d_ws, size_t ws_size,
                              hipStream_t stream) {
    const float* x    = (const float*)d_in[0];
    const float* W    = (const float*)d_in[1];
    const int*   erow = (const int*)d_in[2];
    const int*   ecol = (const int*)d_in[3];
    const float* eval = (const float*)d_in[4];
    float*       out  = (float*)d_out;

    // workspace layout (bytes, 8B-aligned throughout)
    const size_t H_ELEMS = (size_t)N_NODES * OUT_DIM;            // 12.8M
    unsigned short* hb   = (unsigned short*)d_ws;                // bf16 h: 25.6 MB
    unsigned short* Wb   = hb + H_ELEMS;                         // 32768 bf16
    int*            offs = (int*)(Wb + OUT_DIM * IN_DIM);        // PAD_NODES
    int*            cur  = offs + PAD_NODES;                     // PAD_NODES
    int*            bsum = cur + PAD_NODES;                      // 128
    int2*           ccv  = (int2*)(bsum + 128);                  // N_EDGES int2
    const size_t need = ((char*)(ccv + N_EDGES)) - (char*)d_ws;  // ~39.3 MB

    w_to_bf16<<<(OUT_DIM * IN_DIM + 255) / 256, 256, 0, stream>>>(W, Wb);
    gemm_mfma<<<(N_NODES + 127) / 128, 512, 0, stream>>>(x, Wb, hb);

    if (ws_size >= need) {
        hipMemsetAsync(cur, 0, PAD_NODES * sizeof(int), stream);
        hist_rows<<<(N_EDGES + 255) / 256, 256, 0, stream>>>(erow, cur);
        scan_blocks<<<NB_SCAN, 256, 0, stream>>>(cur, offs, bsum);
        scan_bsums<<<1, 64, 0, stream>>>(bsum);
        hipMemsetAsync(cur, 0, PAD_NODES * sizeof(int), stream);
        fill_csr<<<(N_EDGES + 255) / 256, 256, 0, stream>>>(erow, ecol, eval,
                                                            offs, bsum, cur, ccv);
        spmm_gather<<<(N_NODES + 3) / 4, 256, 0, stream>>>(hb, offs, bsum, ccv, out);
    } else {
        hipMemsetAsync(d_out, 0, (size_t)out_size * sizeof(float), stream);
        spmm_scatter<<<8192, 256, 0, stream>>>(hb, erow, ecol, eval, out);
    }
}

// Round 5
// 258.722 us; speedup vs baseline: 11.2610x; 1.2128x over previous
//
#include <hip/hip_runtime.h>
#include <hip/hip_fp16.h>

#define N_NODES 100000
#define N_EDGES 1600000
#define IN_DIM  256
#define OUT_DIM 128

#define SCAN_CHUNK 1024
#define NB_SCAN    98          // ceil(100000/1024)
#define PAD_NODES  (NB_SCAN * SCAN_CHUNK)   // 100352

#define NXCD   8
#define GRP_SZ (N_NODES / NXCD)   // 12500 rows per XCD group (exact)

typedef __attribute__((ext_vector_type(8))) short short8;
typedef __attribute__((ext_vector_type(4))) float f32x4;

// f32 -> bf16 round-to-nearest-even (bit trick)
__device__ __forceinline__ unsigned short f2bf(float f) {
    unsigned int u = __float_as_uint(f);
    u += 0x7FFFu + ((u >> 16) & 1u);
    return (unsigned short)(u >> 16);
}
__device__ __forceinline__ float bf2f(unsigned int u16) {
    return __uint_as_float(u16 << 16);
}

__device__ __forceinline__ short8 pack8(float4 a, float4 b) {
    short8 s;
    s[0] = (short)f2bf(a.x); s[1] = (short)f2bf(a.y);
    s[2] = (short)f2bf(a.z); s[3] = (short)f2bf(a.w);
    s[4] = (short)f2bf(b.x); s[5] = (short)f2bf(b.y);
    s[6] = (short)f2bf(b.z); s[7] = (short)f2bf(b.w);
    return s;
}

// ---------------------------------------------------------------------------
// W (f32 [128][256]) -> bf16
// ---------------------------------------------------------------------------
__global__ __launch_bounds__(256) void w_to_bf16(const float* __restrict__ W,
                                                 unsigned short* __restrict__ Wb) {
    int i = blockIdx.x * 256 + threadIdx.x;
    if (i < OUT_DIM * IN_DIM) Wb[i] = f2bf(W[i]);
}

// ---------------------------------------------------------------------------
// GEMM via bf16 MFMA (unchanged from R4): hb = bf16(x @ W^T)
// ---------------------------------------------------------------------------
__global__ __launch_bounds__(512) void gemm_mfma(const float* __restrict__ x,
                                                 const unsigned short* __restrict__ Wb,
                                                 unsigned short* __restrict__ hb) {
    __shared__ unsigned short xs[128 * 256];   // 64 KB, swizzled
    const int m0  = blockIdx.x * 128;
    const int tid = threadIdx.x;

    {
        const int row = tid >> 2;
        const int cs  = (tid & 3) * 64;
        const int gr  = m0 + row;
        char* lb = (char*)xs;
        if (gr < N_NODES) {
            const float4* src = (const float4*)(x + (size_t)gr * IN_DIM + cs);
#pragma unroll
            for (int i = 0; i < 8; ++i) {
                float4 a = src[2 * i], b = src[2 * i + 1];
                int byt = (row * 512 + (cs + 8 * i) * 2) ^ ((row & 7) << 4);
                *(short8*)(lb + byt) = pack8(a, b);
            }
        } else {
            short8 z = {0, 0, 0, 0, 0, 0, 0, 0};
#pragma unroll
            for (int i = 0; i < 8; ++i) {
                int byt = (row * 512 + (cs + 8 * i) * 2) ^ ((row & 7) << 4);
                *(short8*)(lb + byt) = z;
            }
        }
    }
    __syncthreads();

    const int wid  = tid >> 6;
    const int lane = tid & 63;
    const int l15  = lane & 15;
    const int g8   = (lane >> 4) * 8;

    short8 bf[8];
    const unsigned short* wrow = Wb + (size_t)(wid * 16 + l15) * IN_DIM + g8;
#pragma unroll
    for (int kk = 0; kk < 8; ++kk)
        bf[kk] = *(const short8*)(wrow + kk * 32);

    const int col = wid * 16 + l15;
    const char* lb = (const char*)xs;
    const int sw = (l15 & 7) << 4;

#pragma unroll
    for (int rp = 0; rp < 4; ++rp) {
        const int r0 = rp * 32 + l15;
        const int r1 = r0 + 16;
        short8 a0[8], a1[8];
#pragma unroll
        for (int kk = 0; kk < 8; ++kk) {
            a0[kk] = *(const short8*)(lb + ((r0 * 512 + (kk * 32 + g8) * 2) ^ sw));
            a1[kk] = *(const short8*)(lb + ((r1 * 512 + (kk * 32 + g8) * 2) ^ sw));
        }
        f32x4 acc0 = {0.f, 0.f, 0.f, 0.f}, acc1 = {0.f, 0.f, 0.f, 0.f};
#pragma unroll
        for (int kk = 0; kk < 8; ++kk) {
            acc0 = __builtin_amdgcn_mfma_f32_16x16x32_bf16(a0[kk], bf[kk], acc0, 0, 0, 0);
            acc1 = __builtin_amdgcn_mfma_f32_16x16x32_bf16(a1[kk], bf[kk], acc1, 0, 0, 0);
        }
        const int rb0 = m0 + rp * 32 + (lane >> 4) * 4;
        const int rb1 = rb0 + 16;
#pragma unroll
        for (int i = 0; i < 4; ++i) {
            if (rb0 + i < N_NODES) hb[(size_t)(rb0 + i) * OUT_DIM + col] = f2bf(acc0[i]);
            if (rb1 + i < N_NODES) hb[(size_t)(rb1 + i) * OUT_DIM + col] = f2bf(acc1[i]);
        }
    }
}

// ---------------------------------------------------------------------------
// CSR build
// ---------------------------------------------------------------------------
__global__ __launch_bounds__(256) void hist_rows(const int* __restrict__ erow,
                                                 int* __restrict__ cnt) {
    int e = blockIdx.x * 256 + threadIdx.x;
    if (e < N_EDGES) atomicAdd(&cnt[erow[e]], 1);
}

__global__ __launch_bounds__(256) void scan_blocks(const int* __restrict__ cnt,
                                                   int* __restrict__ offs,
                                                   int* __restrict__ bsum) {
    __shared__ int tmp[256];
    const int t = threadIdx.x;
    const int base = blockIdx.x * SCAN_CHUNK + t * 4;
    int4 v = *(const int4*)(cnt + base);
    int s0 = v.x, s1 = s0 + v.y, s2 = s1 + v.z, s3 = s2 + v.w;
    tmp[t] = s3;
    __syncthreads();
    for (int d = 1; d < 256; d <<= 1) {
        int add = (t >= d) ? tmp[t - d] : 0;
        __syncthreads();
        tmp[t] += add;
        __syncthreads();
    }
    int excl = (t == 0) ? 0 : tmp[t - 1];
    int4 o;
    o.x = excl; o.y = excl + s0; o.z = excl + s1; o.w = excl + s2;
    *(int4*)(offs + base) = o;
    if (t == 255) bsum[blockIdx.x] = tmp[255];
}

// wave-parallel exclusive scan of the 98 chunk sums (was a 1-thread serial loop)
__global__ __launch_bounds__(128) void scan_bsums(int* bsum) {
    __shared__ int tmp[128];
    const int t = threadIdx.x;
    int v = (t < NB_SCAN) ? bsum[t] : 0;
    tmp[t] = v;
    __syncthreads();
    for (int d = 1; d < 128; d <<= 1) {
        int add = (t >= d) ? tmp[t - d] : 0;
        __syncthreads();
        tmp[t] += add;
        __syncthreads();
    }
    if (t < NB_SCAN) bsum[t] = tmp[t] - v;   // exclusive
}

// XCD-cohort fill: block b handles only rows in group (b&7); cohorts
// grid-stride the whole edge list. CSR windows become XCD-exclusive ->
// full-line assembly in local L2, ~1 eviction per 64B line.
// Record: 4B = fp16(val) bits [31:17] | col [16:0].
__global__ __launch_bounds__(256) void fill_csr(const int* __restrict__ erow,
                                                const int* __restrict__ ecol,
                                                const float* __restrict__ eval,
                                                const int* __restrict__ offs,
                                                const int* __restrict__ bsum,
                                                int* __restrict__ cur,
                                                unsigned int* __restrict__ ccv) {
    const int g      = blockIdx.x & (NXCD - 1);
    const int rank   = blockIdx.x >> 3;
    const int stride = (gridDim.x >> 3) * 256;

    for (int e = rank * 256 + threadIdx.x; e < N_EDGES; e += stride) {
        const int r = erow[e];
        if (r / GRP_SZ == g) {
            int pos = offs[r] + bsum[r >> 10] + atomicAdd(&cur[r], 1);
            unsigned int vb = __half_as_ushort(__float2half(eval[e]));
            ccv[pos] = (vb << 17) | (unsigned int)ecol[e];
        }
    }
}

// ---------------------------------------------------------------------------
// Gather: one wave per row; lane owns 2 channels; unroll 4 for MLP.
// ---------------------------------------------------------------------------
__global__ __launch_bounds__(256) void spmm_gather(const unsigned short* __restrict__ hb,
                                                   const int* __restrict__ offs,
                                                   const int* __restrict__ bsum,
                                                   const unsigned int* __restrict__ ccv,
                                                   float* __restrict__ out) {
    const int r = blockIdx.x * 4 + (threadIdx.x >> 6);
    if (r >= N_NODES) return;
    const int lane = threadIdx.x & 63;

    int j         = offs[r]     + bsum[r >> 10];
    const int end = offs[r + 1] + bsum[(r + 1) >> 10];

    float ax = 0.f, ay = 0.f;
    for (; j + 3 < end; j += 4) {
        unsigned int e0 = ccv[j], e1 = ccv[j + 1], e2 = ccv[j + 2], e3 = ccv[j + 3];
        unsigned int p0 = *(const unsigned int*)(hb + (size_t)(e0 & 0x1FFFFu) * OUT_DIM + lane * 2);
        unsigned int p1 = *(const unsigned int*)(hb + (size_t)(e1 & 0x1FFFFu) * OUT_DIM + lane * 2);
        unsigned int p2 = *(const unsigned int*)(hb + (size_t)(e2 & 0x1FFFFu) * OUT_DIM + lane * 2);
        unsigned int p3 = *(const unsigned int*)(hb + (size_t)(e3 & 0x1FFFFu) * OUT_DIM + lane * 2);
        float v0 = __half2float(__ushort_as_half((unsigned short)(e0 >> 17)));
        float v1 = __half2float(__ushort_as_half((unsigned short)(e1 >> 17)));
        float v2 = __half2float(__ushort_as_half((unsigned short)(e2 >> 17)));
        float v3 = __half2float(__ushort_as_half((unsigned short)(e3 >> 17)));
        ax += v0 * bf2f(p0 & 0xFFFFu) + v1 * bf2f(p1 & 0xFFFFu)
            + v2 * bf2f(p2 & 0xFFFFu) + v3 * bf2f(p3 & 0xFFFFu);
        ay += v0 * bf2f(p0 >> 16) + v1 * bf2f(p1 >> 16)
            + v2 * bf2f(p2 >> 16) + v3 * bf2f(p3 >> 16);
    }
    for (; j < end; ++j) {
        unsigned int e0 = ccv[j];
        float v0 = __half2float(__ushort_as_half((unsigned short)(e0 >> 17)));
        unsigned int p0 = *(const unsigned int*)(hb + (size_t)(e0 & 0x1FFFFu) * OUT_DIM + lane * 2);
        ax += v0 * bf2f(p0 & 0xFFFFu);
        ay += v0 * bf2f(p0 >> 16);
    }
    float2 o = {ax, ay};
    *(float2*)(out + (size_t)r * OUT_DIM + lane * 2) = o;
}

// ---------------------------------------------------------------------------
// Fallback scatter (bf16 h) if workspace too small for CSR.
// ---------------------------------------------------------------------------
__global__ __launch_bounds__(256) void spmm_scatter(const unsigned short* __restrict__ hb,
                                                    const int* __restrict__ erow,
                                                    const int* __restrict__ ecol,
                                                    const float* __restrict__ eval,
                                                    float* __restrict__ out) {
    const int lane = threadIdx.x & 63;
    const int eloc = threadIdx.x >> 6;
    const int stride = gridDim.x * 4;
    for (int e = blockIdx.x * 4 + eloc; e < N_EDGES; e += stride) {
        const int r = erow[e];
        const int c = ecol[e];
        const float v = eval[e];
        unsigned int p = *(const unsigned int*)(hb + (size_t)c * OUT_DIM + lane * 2);
        float* o = out + (size_t)r * OUT_DIM + lane * 2;
        unsafeAtomicAdd(o + 0, v * bf2f(p & 0xFFFFu));
        unsafeAtomicAdd(o + 1, v * bf2f(p >> 16));
    }
}

extern "C" void kernel_launch(void* const* d_in, const int* in_sizes, int n_in,
                              void* d_out, int out_size, void* d_ws, size_t ws_size,
                              hipStream_t stream) {
    const float* x    = (const float*)d_in[0];
    const float* W    = (const float*)d_in[1];
    const int*   erow = (const int*)d_in[2];
    const int*   ecol = (const int*)d_in[3];
    const float* eval = (const float*)d_in[4];
    float*       out  = (float*)d_out;

    // workspace layout
    const size_t H_ELEMS = (size_t)N_NODES * OUT_DIM;
    unsigned short* hb   = (unsigned short*)d_ws;                // 25.6 MB
    unsigned short* Wb   = hb + H_ELEMS;                         // 64 KB
    int*            offs = (int*)(Wb + OUT_DIM * IN_DIM);        // PAD_NODES
    int*            cur  = offs + PAD_NODES;                     // PAD_NODES
    int*            bsum = cur + PAD_NODES;                      // 128
    unsigned int*   ccv  = (unsigned int*)(bsum + 128);          // N_EDGES u32 (6.4 MB)
    const size_t need = ((char*)(ccv + N_EDGES)) - (char*)d_ws;  // ~33 MB

    w_to_bf16<<<(OUT_DIM * IN_DIM + 255) / 256, 256, 0, stream>>>(W, Wb);
    gemm_mfma<<<(N_NODES + 127) / 128, 512, 0, stream>>>(x, Wb, hb);

    if (ws_size >= need) {
        hipMemsetAsync(cur, 0, PAD_NODES * sizeof(int), stream);
        hist_rows<<<(N_EDGES + 255) / 256, 256, 0, stream>>>(erow, cur);
        scan_blocks<<<NB_SCAN, 256, 0, stream>>>(cur, offs, bsum);
        scan_bsums<<<1, 128, 0, stream>>>(bsum);
        hipMemsetAsync(cur, 0, PAD_NODES * sizeof(int), stream);
        fill_csr<<<2048, 256, 0, stream>>>(erow, ecol, eval, offs, bsum, cur, ccv);
        spmm_gather<<<(N_NODES + 3) / 4, 256, 0, stream>>>(hb, offs, bsum, ccv, out);
    } else {
        hipMemsetAsync(d_out, 0, (size_t)out_size * sizeof(float), stream);
        spmm_scatter<<<8192, 256, 0, stream>>>(hb, erow, ecol, eval, out);
    }
}

// Round 6
// 177.721 us; speedup vs baseline: 16.3935x; 1.4558x over previous
//
#include <hip/hip_runtime.h>
#include <hip/hip_fp16.h>

#define N_NODES 100000
#define N_EDGES 1600000
#define IN_DIM  256
#define OUT_DIM 128

#define NBKT   196            // buckets of 512 rows: ceil(100000/512)
#define BROWS  512
#define CHUNK  8192           // edges per bin block: 196*8192 >= N_EDGES
#define DCAP   12288          // max records sorted in LDS (48 KB); mean 8192, sigma~90

typedef __attribute__((ext_vector_type(8))) short short8;
typedef __attribute__((ext_vector_type(4))) float f32x4;

// f32 -> bf16 round-to-nearest-even (bit trick)
__device__ __forceinline__ unsigned short f2bf(float f) {
    unsigned int u = __float_as_uint(f);
    u += 0x7FFFu + ((u >> 16) & 1u);
    return (unsigned short)(u >> 16);
}
__device__ __forceinline__ float bf2f(unsigned int u16) {
    return __uint_as_float(u16 << 16);
}

__device__ __forceinline__ short8 pack8(float4 a, float4 b) {
    short8 s;
    s[0] = (short)f2bf(a.x); s[1] = (short)f2bf(a.y);
    s[2] = (short)f2bf(a.z); s[3] = (short)f2bf(a.w);
    s[4] = (short)f2bf(b.x); s[5] = (short)f2bf(b.y);
    s[6] = (short)f2bf(b.z); s[7] = (short)f2bf(b.w);
    return s;
}

// ---------------------------------------------------------------------------
// W (f32 [128][256]) -> bf16
// ---------------------------------------------------------------------------
__global__ __launch_bounds__(256) void w_to_bf16(const float* __restrict__ W,
                                                 unsigned short* __restrict__ Wb) {
    int i = blockIdx.x * 256 + threadIdx.x;
    if (i < OUT_DIM * IN_DIM) Wb[i] = f2bf(W[i]);
}

// ---------------------------------------------------------------------------
// GEMM via bf16 MFMA (unchanged): hb = bf16(x @ W^T)
// ---------------------------------------------------------------------------
__global__ __launch_bounds__(512) void gemm_mfma(const float* __restrict__ x,
                                                 const unsigned short* __restrict__ Wb,
                                                 unsigned short* __restrict__ hb) {
    __shared__ unsigned short xs[128 * 256];   // 64 KB, swizzled
    const int m0  = blockIdx.x * 128;
    const int tid = threadIdx.x;

    {
        const int row = tid >> 2;
        const int cs  = (tid & 3) * 64;
        const int gr  = m0 + row;
        char* lb = (char*)xs;
        if (gr < N_NODES) {
            const float4* src = (const float4*)(x + (size_t)gr * IN_DIM + cs);
#pragma unroll
            for (int i = 0; i < 8; ++i) {
                float4 a = src[2 * i], b = src[2 * i + 1];
                int byt = (row * 512 + (cs + 8 * i) * 2) ^ ((row & 7) << 4);
                *(short8*)(lb + byt) = pack8(a, b);
            }
        } else {
            short8 z = {0, 0, 0, 0, 0, 0, 0, 0};
#pragma unroll
            for (int i = 0; i < 8; ++i) {
                int byt = (row * 512 + (cs + 8 * i) * 2) ^ ((row & 7) << 4);
                *(short8*)(lb + byt) = z;
            }
        }
    }
    __syncthreads();

    const int wid  = tid >> 6;
    const int lane = tid & 63;
    const int l15  = lane & 15;
    const int g8   = (lane >> 4) * 8;

    short8 bf[8];
    const unsigned short* wrow = Wb + (size_t)(wid * 16 + l15) * IN_DIM + g8;
#pragma unroll
    for (int kk = 0; kk < 8; ++kk)
        bf[kk] = *(const short8*)(wrow + kk * 32);

    const int col = wid * 16 + l15;
    const char* lb = (const char*)xs;
    const int sw = (l15 & 7) << 4;

#pragma unroll
    for (int rp = 0; rp < 4; ++rp) {
        const int r0 = rp * 32 + l15;
        const int r1 = r0 + 16;
        short8 a0[8], a1[8];
#pragma unroll
        for (int kk = 0; kk < 8; ++kk) {
            a0[kk] = *(const short8*)(lb + ((r0 * 512 + (kk * 32 + g8) * 2) ^ sw));
            a1[kk] = *(const short8*)(lb + ((r1 * 512 + (kk * 32 + g8) * 2) ^ sw));
        }
        f32x4 acc0 = {0.f, 0.f, 0.f, 0.f}, acc1 = {0.f, 0.f, 0.f, 0.f};
#pragma unroll
        for (int kk = 0; kk < 8; ++kk) {
            acc0 = __builtin_amdgcn_mfma_f32_16x16x32_bf16(a0[kk], bf[kk], acc0, 0, 0, 0);
            acc1 = __builtin_amdgcn_mfma_f32_16x16x32_bf16(a1[kk], bf[kk], acc1, 0, 0, 0);
        }
        const int rb0 = m0 + rp * 32 + (lane >> 4) * 4;
        const int rb1 = rb0 + 16;
#pragma unroll
        for (int i = 0; i < 4; ++i) {
            if (rb0 + i < N_NODES) hb[(size_t)(rb0 + i) * OUT_DIM + col] = f2bf(acc0[i]);
            if (rb1 + i < N_NODES) hb[(size_t)(rb1 + i) * OUT_DIM + col] = f2bf(acc1[i]);
        }
    }
}

// ---------------------------------------------------------------------------
// Phase A: 196-bucket histogram (bucket = 512 rows)
// ---------------------------------------------------------------------------
__global__ __launch_bounds__(256) void bucket_hist(const int* __restrict__ erow,
                                                   int* __restrict__ bcnt) {
    __shared__ int h[NBKT];
    for (int i = threadIdx.x; i < NBKT; i += 256) h[i] = 0;
    __syncthreads();
    const int e0 = blockIdx.x * CHUNK;
    for (int i = threadIdx.x; i < CHUNK; i += 256) {
        int e = e0 + i;
        if (e < N_EDGES) atomicAdd(&h[erow[e] >> 9], 1);
    }
    __syncthreads();
    for (int i = threadIdx.x; i < NBKT; i += 256)
        if (h[i]) atomicAdd(&bcnt[i], h[i]);
}

// ---------------------------------------------------------------------------
// Phase B: exclusive scan of 196 bucket counts -> bbase[197], init bcur
// ---------------------------------------------------------------------------
__global__ __launch_bounds__(256) void bucket_scan(const int* __restrict__ bcnt,
                                                   int* __restrict__ bbase,
                                                   int* __restrict__ bcur) {
    __shared__ int tmp[256];
    const int t = threadIdx.x;
    int v = (t < NBKT) ? bcnt[t] : 0;
    tmp[t] = v;
    __syncthreads();
    for (int d = 1; d < 256; d <<= 1) {
        int a = (t >= d) ? tmp[t - d] : 0;
        __syncthreads();
        tmp[t] += a;
        __syncthreads();
    }
    if (t < NBKT) {
        int ex = tmp[t] - v;
        bbase[t] = ex;
        bcur[t]  = ex;
    }
    if (t == 0) bbase[NBKT] = tmp[NBKT - 1];
}

// ---------------------------------------------------------------------------
// Phase C: bin pass. Block owns a contiguous 8192-edge chunk; reserves ONE
// contiguous run per (block,bucket) with a single atomicAdd, then places
// int2{rec,row} records into its private runs. Runs are block-exclusive ->
// full 64B lines assemble in the local L2 and evict once.
// rec = fp16(val)<<17 | col.
// ---------------------------------------------------------------------------
__global__ __launch_bounds__(256) void bin_pass(const int* __restrict__ erow,
                                                const int* __restrict__ ecol,
                                                const float* __restrict__ eval,
                                                int* __restrict__ bcur,
                                                int2* __restrict__ gbuf) {
    __shared__ int h[NBKT], gpos[NBKT], rcur[NBKT];
    for (int i = threadIdx.x; i < NBKT; i += 256) { h[i] = 0; rcur[i] = 0; }
    __syncthreads();
    const int e0 = blockIdx.x * CHUNK;
    for (int i = threadIdx.x; i < CHUNK; i += 256) {
        int e = e0 + i;
        if (e < N_EDGES) atomicAdd(&h[erow[e] >> 9], 1);
    }
    __syncthreads();
    for (int i = threadIdx.x; i < NBKT; i += 256)
        gpos[i] = h[i] ? atomicAdd(&bcur[i], h[i]) : 0;
    __syncthreads();
    for (int i = threadIdx.x; i < CHUNK; i += 256) {
        int e = e0 + i;
        if (e < N_EDGES) {
            int r = erow[e];
            int b = r >> 9;
            unsigned int vb  = __half_as_ushort(__float2half(eval[e]));
            unsigned int rec = (vb << 17) | (unsigned int)ecol[e];
            int pos = gpos[b] + atomicAdd(&rcur[b], 1);
            gbuf[pos] = make_int2((int)rec, r);
        }
    }
}

// ---------------------------------------------------------------------------
// Phase D: per-bucket LDS counting sort -> compact 4B CSR + absolute offs.
// Block b: hist 512 rows, scan, ranked scatter into LDS, coalesced writeout.
// offs[r0+i] = bbase[b] + excl_scan[i]; note offs[100000] lands = total.
// ---------------------------------------------------------------------------
__global__ __launch_bounds__(256) void sort_bucket(const int2* __restrict__ gbuf,
                                                   const int* __restrict__ bbase,
                                                   unsigned int* __restrict__ gcsr,
                                                   int* __restrict__ offs) {
    __shared__ int rh[BROWS], rc[BROWS];
    __shared__ int tmp[256];
    __shared__ unsigned int lout[DCAP];
    const int b    = blockIdx.x;
    const int base = bbase[b];
    const int cnt  = bbase[b + 1] - base;
    const int r0   = b * BROWS;
    const int t    = threadIdx.x;

    rh[2 * t] = 0; rh[2 * t + 1] = 0;
    __syncthreads();
    for (int i = t; i < cnt; i += 256)
        atomicAdd(&rh[gbuf[base + i].y - r0], 1);
    __syncthreads();

    // exclusive scan of 512 with 256 threads (2 elems each)
    int a0 = rh[2 * t], a1 = rh[2 * t + 1], s = a0 + a1;
    tmp[t] = s;
    __syncthreads();
    for (int d = 1; d < 256; d <<= 1) {
        int a = (t >= d) ? tmp[t - d] : 0;
        __syncthreads();
        tmp[t] += a;
        __syncthreads();
    }
    int ex = tmp[t] - s;
    rc[2 * t]     = ex;
    rc[2 * t + 1] = ex + a0;
    offs[r0 + 2 * t]     = base + ex;
    offs[r0 + 2 * t + 1] = base + ex + a0;
    __syncthreads();

    if (cnt <= DCAP) {
        for (int i = t; i < cnt; i += 256) {
            int2 rr = gbuf[base + i];
            int p = atomicAdd(&rc[rr.y - r0], 1);
            lout[p] = (unsigned int)rr.x;
        }
        __syncthreads();
        for (int i = t; i < cnt; i += 256)
            gcsr[base + i] = lout[i];
    } else {  // statistically unreachable; correctness fallback
        for (int i = t; i < cnt; i += 256) {
            int2 rr = gbuf[base + i];
            int p = atomicAdd(&rc[rr.y - r0], 1);
            gcsr[base + p] = (unsigned int)rr.x;
        }
    }
}

// ---------------------------------------------------------------------------
// Gather: one wave per row; lane owns 2 channels; unroll 8.
// ---------------------------------------------------------------------------
__global__ __launch_bounds__(256) void spmm_gather(const unsigned short* __restrict__ hb,
                                                   const int* __restrict__ offs,
                                                   const unsigned int* __restrict__ ccv,
                                                   float* __restrict__ out) {
    const int r = blockIdx.x * 4 + (threadIdx.x >> 6);
    if (r >= N_NODES) return;
    const int lane = threadIdx.x & 63;

    int j         = offs[r];
    const int end = offs[r + 1];

    float ax = 0.f, ay = 0.f;
    for (; j + 7 < end; j += 8) {
        unsigned int e[8], p[8];
#pragma unroll
        for (int q = 0; q < 8; ++q) e[q] = ccv[j + q];
#pragma unroll
        for (int q = 0; q < 8; ++q)
            p[q] = *(const unsigned int*)(hb + (size_t)(e[q] & 0x1FFFFu) * OUT_DIM + lane * 2);
#pragma unroll
        for (int q = 0; q < 8; ++q) {
            float v = __half2float(__ushort_as_half((unsigned short)(e[q] >> 17)));
            ax += v * bf2f(p[q] & 0xFFFFu);
            ay += v * bf2f(p[q] >> 16);
        }
    }
    for (; j < end; ++j) {
        unsigned int e0 = ccv[j];
        float v0 = __half2float(__ushort_as_half((unsigned short)(e0 >> 17)));
        unsigned int p0 = *(const unsigned int*)(hb + (size_t)(e0 & 0x1FFFFu) * OUT_DIM + lane * 2);
        ax += v0 * bf2f(p0 & 0xFFFFu);
        ay += v0 * bf2f(p0 >> 16);
    }
    float2 o = {ax, ay};
    *(float2*)(out + (size_t)r * OUT_DIM + lane * 2) = o;
}

// ---------------------------------------------------------------------------
// Fallback scatter (bf16 h) if workspace too small.
// ---------------------------------------------------------------------------
__global__ __launch_bounds__(256) void spmm_scatter(const unsigned short* __restrict__ hb,
                                                    const int* __restrict__ erow,
                                                    const int* __restrict__ ecol,
                                                    const float* __restrict__ eval,
                                                    float* __restrict__ out) {
    const int lane = threadIdx.x & 63;
    const int eloc = threadIdx.x >> 6;
    const int stride = gridDim.x * 4;
    for (int e = blockIdx.x * 4 + eloc; e < N_EDGES; e += stride) {
        const int r = erow[e];
        const int c = ecol[e];
        const float v = eval[e];
        unsigned int p = *(const unsigned int*)(hb + (size_t)c * OUT_DIM + lane * 2);
        float* o = out + (size_t)r * OUT_DIM + lane * 2;
        unsafeAtomicAdd(o + 0, v * bf2f(p & 0xFFFFu));
        unsafeAtomicAdd(o + 1, v * bf2f(p >> 16));
    }
}

extern "C" void kernel_launch(void* const* d_in, const int* in_sizes, int n_in,
                              void* d_out, int out_size, void* d_ws, size_t ws_size,
                              hipStream_t stream) {
    const float* x    = (const float*)d_in[0];
    const float* W    = (const float*)d_in[1];
    const int*   erow = (const int*)d_in[2];
    const int*   ecol = (const int*)d_in[3];
    const float* eval = (const float*)d_in[4];
    float*       out  = (float*)d_out;

    // workspace layout (8B-aligned boundaries)
    const size_t H_ELEMS = (size_t)N_NODES * OUT_DIM;            // 12.8M
    unsigned short* hb   = (unsigned short*)d_ws;                // 25.6 MB
    unsigned short* Wb   = hb + H_ELEMS;                         // 64 KB
    int2*           gbuf = (int2*)(Wb + OUT_DIM * IN_DIM);       // 12.8 MB
    unsigned int*   gcsr = (unsigned int*)(gbuf + N_EDGES);      // 6.4 MB
    int*            offs = (int*)(gcsr + N_EDGES);               // (NBKT*BROWS+8) ints
    int*            bcnt = offs + NBKT * BROWS + 8;              // NBKT
    int*            bbase = bcnt + NBKT;                         // NBKT+1
    int*            bcur  = bbase + NBKT + 1;                    // NBKT
    const size_t need = ((char*)(bcur + NBKT)) - (char*)d_ws;    // ~45.6 MB

    w_to_bf16<<<(OUT_DIM * IN_DIM + 255) / 256, 256, 0, stream>>>(W, Wb);
    gemm_mfma<<<(N_NODES + 127) / 128, 512, 0, stream>>>(x, Wb, hb);

    if (ws_size >= need) {
        hipMemsetAsync(bcnt, 0, NBKT * sizeof(int), stream);
        bucket_hist<<<NBKT, 256, 0, stream>>>(erow, bcnt);
        bucket_scan<<<1, 256, 0, stream>>>(bcnt, bbase, bcur);
        bin_pass<<<NBKT, 256, 0, stream>>>(erow, ecol, eval, bcur, gbuf);
        sort_bucket<<<NBKT, 256, 0, stream>>>(gbuf, bbase, gcsr, offs);
        spmm_gather<<<(N_NODES + 3) / 4, 256, 0, stream>>>(hb, offs, gcsr, out);
    } else {
        hipMemsetAsync(d_out, 0, (size_t)out_size * sizeof(float), stream);
        spmm_scatter<<<8192, 256, 0, stream>>>(hb, erow, ecol, eval, out);
    }
}